// Round 18
// baseline (318.442 us; speedup 1.0000x reference)
//
#include <hip/hip_runtime.h>
#include <hip/hip_bf16.h>

static constexpr int CH   = 256;
static constexpr int NHD  = 4;
static constexpr int DV   = 64;
static constexpr int SY = 48, SX = 48, SZ = 48;
static constexpr int NPEN = SY * SX;     // 2304
static constexpr int NPOS = NPEN * SZ;   // 110592
static constexpr int PF2  = 128 * 80;    // kv partial floats per block

typedef float f32x4 __attribute__((ext_vector_type(4)));
typedef short bf8   __attribute__((ext_vector_type(8)));
union U16x4 { uint4 u; bf8 h; };

__device__ __forceinline__ ushort f2bf(float f) {
  return __bfloat16_as_ushort(__float2bfloat16(f));
}
__device__ __forceinline__ uint pk2(float lo, float hi) {
  return ((uint)f2bf(hi) << 16) | (uint)f2bf(lo);
}

// ---------------------------------------------------------------------------
// Prep: Wqk2 bf16 [256 rows][256 c], per-head blocks.
// ---------------------------------------------------------------------------
__global__ __launch_bounds__(256) void k_prep2(
    const float* __restrict__ Wq, const float* __restrict__ Wk,
    ushort* __restrict__ Wqk2)
{
  const int i = blockIdx.x * 256 + threadIdx.x;   // grid 256 -> 65536
  const int rp = i >> 8, c = i & 255;
  const int h = rp >> 6, s = (rp >> 5) & 1, j = rp & 31;
  const float v = s ? Wk[(h * 32 + j) * 256 + c] : Wq[(h * 32 + j) * 256 + c];
  Wqk2[i] = f2bf(v);
}

// ---------------------------------------------------------------------------
// k_conv3: depthwise 3x3x3 conv + bias -> v (bf16). BARRIER-FREE.
// Each wave owns 16 x-columns + a private 2-slot plane ring ([2][18*51] f32,
// 7.3 KB/wave). Staging/ds_write/window-reads all wave-internal -> program
// order + compiler waitcnts suffice; ZERO __syncthreads in the hot loop.
// Partial-sum carry (r17): each plane folded exactly once -> 2 slots enough.
// x-halo (2 cols/wave) re-fetched from global (+12.5% FETCH).
// ---------------------------------------------------------------------------
__global__ __launch_bounds__(192) void k_conv3(
    const float* __restrict__ x, const float* __restrict__ Wv,
    const float* __restrict__ bv, __hip_bfloat16* __restrict__ vbuf,
    int y0s, int ys, int nyc)
{
  __shared__ float ring[3][2][18 * 51];  // per-wave private, 22.0 KB total

  const int t    = threadIdx.x;
  const int lane = t & 63;
  const int w    = __builtin_amdgcn_readfirstlane(t >> 6);
  const int bid  = blockIdx.x;
  const int yc   = bid % nyc;
  const int c    = (bid / nyc) & 255;
  const int b    = bid / (nyc * 256);
  const int yst  = y0s + yc * 12;
  const int x0   = w * 16;               // wave's x-range [x0, x0+16)

  const int cu = __builtin_amdgcn_readfirstlane(c);
  const float* xc = x + (size_t)(b * CH + cu) * NPOS;
  float wreg[27];
#pragma unroll
  for (int j = 0; j < 27; ++j) wreg[j] = Wv[cu * 27 + j];
  const float bias = bv[cu];

  float* my0 = &ring[w][0][0];
  float* my1 = &ring[w][1][0];
  // zero own 2 planes (pads at rel idx 0 and 49 per col stay 0 forever;
  // in-range cells are overwritten by SWRITE each plane)
  for (int i = lane; i < 2 * 18 * 51; i += 64) my0[i] = 0.f;

  // staging: 18 cols x 12 z-quads = 216 16B chunks per plane, 64 lanes x <=4
  const int cid0 = lane, cid1 = lane + 64, cid2 = lane + 128, cid3 = lane + 192;
  const bool has3 = (lane < 24);         // cid3 < 216
  const int co0 = (cid0 / 12) * 51 + 1 + (cid0 % 12) * 4;
  const int co1 = (cid1 / 12) * 51 + 1 + (cid1 % 12) * 4;
  const int co2 = (cid2 / 12) * 51 + 1 + (cid2 % 12) * 4;
  const int co3 = ((has3 ? cid3 : 192) / 12) * 51 + 1 + ((has3 ? cid3 : 192) % 12) * 4;
  // global offsets (gx = x0-1+col may be out of [0,48))
  int  go0, go1, go2, go3;
  bool gv0, gv1, gv2, gv3;
  {
    const int g0 = x0 - 1 + cid0 / 12, g1 = x0 - 1 + cid1 / 12;
    const int g2 = x0 - 1 + cid2 / 12, g3 = x0 - 1 + cid3 / 12;
    gv0 = (unsigned)g0 < 48u; gv1 = (unsigned)g1 < 48u;
    gv2 = (unsigned)g2 < 48u; gv3 = has3 && ((unsigned)g3 < 48u);
    go0 = g0 * SZ + (cid0 % 12) * 4;  go1 = g1 * SZ + (cid1 % 12) * 4;
    go2 = g2 * SZ + (cid2 % 12) * 4;  go3 = g3 * SZ + (cid3 % 12) * 4;
  }

  float4 v0, v1, v2, v3;

#define SISSUE(gy_)                                                           \
  {                                                                           \
    const int g_ = (gy_);                                                     \
    if ((unsigned)g_ < 48u) {                                                 \
      const float* rp_ = xc + (size_t)g_ * NPEN;                              \
      v0 = gv0 ? *(const float4*)(rp_ + go0) : (float4){0.f,0.f,0.f,0.f};     \
      v1 = gv1 ? *(const float4*)(rp_ + go1) : (float4){0.f,0.f,0.f,0.f};     \
      v2 = gv2 ? *(const float4*)(rp_ + go2) : (float4){0.f,0.f,0.f,0.f};     \
      v3 = gv3 ? *(const float4*)(rp_ + go3) : (float4){0.f,0.f,0.f,0.f};     \
    } else {                                                                  \
      v0 = (float4){0.f,0.f,0.f,0.f}; v1 = v0; v2 = v0; v3 = v0;              \
    }                                                                         \
  }

#define SWRITE(PL_)                                                           \
  {                                                                           \
    float* pl_ = (PL_);                                                       \
    pl_[co0+0]=v0.x; pl_[co0+1]=v0.y; pl_[co0+2]=v0.z; pl_[co0+3]=v0.w;       \
    pl_[co1+0]=v1.x; pl_[co1+1]=v1.y; pl_[co1+2]=v1.z; pl_[co1+3]=v1.w;       \
    pl_[co2+0]=v2.x; pl_[co2+1]=v2.y; pl_[co2+2]=v2.z; pl_[co2+3]=v2.w;       \
    if (has3) {                                                               \
      pl_[co3+0]=v3.x; pl_[co3+1]=v3.y; pl_[co3+2]=v3.z; pl_[co3+3]=v3.w;     \
    }                                                                         \
  }

  const int xl = lane >> 2;              // 0..15 local x
  const int zb = (lane & 3) * 12;

  float accP[12], accQ[12], accN[12];
#pragma unroll
  for (int i = 0; i < 12; ++i) { accP[i] = bias; accQ[i] = bias; }

  // FOLD3: plane PL_ -> accP += w2*p, accQ += w1*p, accN += w0*p
#define FOLD3(PL_)                                                            \
  {                                                                           \
    const float* P_ = (PL_);                                                  \
    _Pragma("unroll")                                                         \
    for (int dx = 0; dx < 3; ++dx) {                                          \
      const float* B_ = P_ + (xl + dx) * 51 + zb;                             \
      float col[14];                                                          \
      _Pragma("unroll")                                                       \
      for (int k = 0; k < 14; ++k) col[k] = B_[k];                            \
      _Pragma("unroll")                                                       \
      for (int dz = 0; dz < 3; ++dz) {                                        \
        const float w2_ = wreg[18 + dx * 3 + dz];                             \
        const float w1_ = wreg[9  + dx * 3 + dz];                             \
        const float w0_ = wreg[     dx * 3 + dz];                             \
        _Pragma("unroll")                                                     \
        for (int i = 0; i < 12; ++i) {                                        \
          accP[i] = fmaf(w2_, col[i + dz], accP[i]);                          \
          accQ[i] = fmaf(w1_, col[i + dz], accQ[i]);                          \
          accN[i] = fmaf(w0_, col[i + dz], accN[i]);                          \
        }                                                                     \
      }                                                                       \
    }                                                                         \
  }

#define STORE(r_)                                                             \
  {                                                                           \
    const size_t o_ = (size_t)(b * CH + cu) * ((size_t)ys * NPEN) +           \
                      (size_t)(yst - y0s + (r_)) * NPEN + (x0 + xl) * SZ + zb;\
    uint2 s0_, s1_, s2_;                                                      \
    s0_.x = pk2(accP[0], accP[1]);  s0_.y = pk2(accP[2],  accP[3]);           \
    s1_.x = pk2(accP[4], accP[5]);  s1_.y = pk2(accP[6],  accP[7]);           \
    s2_.x = pk2(accP[8], accP[9]);  s2_.y = pk2(accP[10], accP[11]);          \
    __hip_bfloat16* dst_ = vbuf + o_;                                         \
    *(uint2*)(dst_)     = s0_;                                                \
    *(uint2*)(dst_ + 4) = s1_;                                                \
    *(uint2*)(dst_ + 8) = s2_;                                                \
  }

#define ROWPHASE(r_, PF_, PW_)                                                \
  {                                                                           \
    if ((r_) < 11) SISSUE(yst + (r_) + 2)                                     \
    _Pragma("unroll")                                                         \
    for (int i = 0; i < 12; ++i) accN[i] = bias;                              \
    FOLD3(PF_)                         /* plane r+1 */                        \
    STORE(r_)                                                                 \
    _Pragma("unroll")                                                         \
    for (int i = 0; i < 12; ++i) { accP[i] = accQ[i]; accQ[i] = accN[i]; }    \
    if ((r_) < 11) SWRITE(PW_)         /* plane r+2 */                        \
  }

  // ---- prologue (wave-private, no barriers) ----
  SISSUE(yst - 1) SWRITE(my0)            // plane -1 -> slot0
  SISSUE(yst)                            // plane 0 in regs
  // fold plane -1: w0 -> accP (row 0)
  {
    const float* P_ = my0;
#pragma unroll
    for (int dx = 0; dx < 3; ++dx) {
      const float* B_ = P_ + (xl + dx) * 51 + zb;
      float col[14];
#pragma unroll
      for (int k = 0; k < 14; ++k) col[k] = B_[k];
#pragma unroll
      for (int dz = 0; dz < 3; ++dz) {
        const float w0_ = wreg[dx * 3 + dz];
#pragma unroll
        for (int i = 0; i < 12; ++i)
          accP[i] = fmaf(w0_, col[i + dz], accP[i]);
      }
    }
  }
  SWRITE(my1)                            // plane 0 -> slot1
  SISSUE(yst + 1)                        // plane 1 in regs
  // fold plane 0: w1 -> accP (row 0), w0 -> accQ (row 1)
  {
    const float* P_ = my1;
#pragma unroll
    for (int dx = 0; dx < 3; ++dx) {
      const float* B_ = P_ + (xl + dx) * 51 + zb;
      float col[14];
#pragma unroll
      for (int k = 0; k < 14; ++k) col[k] = B_[k];
#pragma unroll
      for (int dz = 0; dz < 3; ++dz) {
        const float w1_ = wreg[9 + dx * 3 + dz];
        const float w0_ = wreg[    dx * 3 + dz];
#pragma unroll
        for (int i = 0; i < 12; ++i) {
          accP[i] = fmaf(w1_, col[i + dz], accP[i]);
          accQ[i] = fmaf(w0_, col[i + dz], accQ[i]);
        }
      }
    }
  }
  SWRITE(my0)                            // plane 1 -> slot0 (plane -1 done)

  // ---- 12 rows, 2-phase static slot ping-pong, no barriers ----
#pragma unroll
  for (int g = 0; g < 6; ++g) {
    ROWPHASE(g * 2 + 0, my0, my1)        // fold plane r+1 (slot0), write r+2
    ROWPHASE(g * 2 + 1, my1, my0)
  }
#undef ROWPHASE
#undef STORE
#undef FOLD3
#undef SISSUE
#undef SWRITE
}

// ---------------------------------------------------------------------------
// k_fuse: 512 thr, 8 waves. wave w -> head h=w>>1, n-half nh=w&1.
// Double-buffered gload_lds x-tile; rotated bank-free layout; transposed qsm.
// (unchanged from rounds 12-17)
// ---------------------------------------------------------------------------
__global__ __launch_bounds__(512) void k_fuse(
    const float* __restrict__ x, const ushort* __restrict__ Wqk2,
    const ushort* __restrict__ vbuf, uint* __restrict__ qsm,
    float* __restrict__ partials, int y0s, int ys, int first, int nbh)
{
  __shared__ float xf[2][CH * 64];      // 2 x 64 KB f32 x-tile [c][64n] rotated
  __shared__ short scr[8 * 32 * 40];    // per-wave wexp [kc][40] (80B rows)

  const int t    = threadIdx.x;
  const int lane = t & 63;
  const int w    = __builtin_amdgcn_readfirstlane(t >> 6);
  const int h    = w >> 1, nh = w & 1;
  const int l15  = lane & 15, lg = lane >> 4;
  const int bid  = blockIdx.x;
  const int b    = (bid >= nbh) ? 1 : 0;
  const int bh   = bid - b * nbh;
  const int ntiles = ys * 36;
  const size_t Nsl = (size_t)ys * NPEN;

  const float*  xb = x + (size_t)b * CH * NPOS + (size_t)y0s * NPEN;
  const ushort* vb = vbuf + (size_t)(b * CH + h * 64) * Nsl;
  short* myscr = &scr[w * 32 * 40];
  const int gn_base = y0s * NPEN + nh * 32 + l15;
  uint* qhead = qsm + (size_t)(b * 4 + h) * 16 * NPOS;

  bf8 Bones;
  {
    const short o = (l15 == 0) ? (short)0x3F80 : (short)0;
#pragma unroll
    for (int j = 0; j < 8; ++j) Bones[j] = o;
  }

  f32x4 C2[2][5];
#pragma unroll
  for (int i = 0; i < 2; ++i)
#pragma unroll
    for (int j = 0; j < 5; ++j) C2[i][j] = (f32x4){0.f, 0.f, 0.f, 0.f};

  const int nr0 = (nh * 32 + 0  + l15 + lg * 8) & 63;
  const int nr1 = (nh * 32 + 16 + l15 + lg * 8) & 63;

#define STAGE(tile_, buf_)                                                     \
  {                                                                            \
    const int n0_ = (tile_) * 64;                                              \
    _Pragma("unroll")                                                          \
    for (int j_ = 0; j_ < 8; ++j_) {                                           \
      const int k_  = j_ * 512 + t;           /* 16B chunk id, 0..4095 */      \
      const int c_  = k_ >> 4;                                                 \
      const int ci_ = k_ & 15;                                                 \
      const int rot_ = ((c_ >> 3) & 3) << 1;  /* rotation in 16B chunks */     \
      const int nq_  = ((ci_ - rot_) & 15) << 2;                               \
      const float* src_ = xb + (size_t)c_ * NPOS + n0_ + nq_;                  \
      __builtin_amdgcn_global_load_lds(                                        \
          (const __attribute__((address_space(1))) void*)src_,                 \
          (__attribute__((address_space(3))) void*)((char*)xf +                \
              ((buf_) * 4096 + j_ * 512 + w * 64) * 16),                       \
          16, 0, 0);                                                           \
    }                                                                          \
  }

  int cur = 0;
  if (bh < ntiles) STAGE(bh, 0)

  for (int tile = bh; tile < ntiles; tile += nbh) {
    const int n0 = tile * 64;
    __syncthreads();                       // xf[cur] ready (drain); waves sync

    if (tile + nbh < ntiles) STAGE(tile + nbh, cur ^ 1)

    uint4 vr[4];
#pragma unroll
    for (int ct = 0; ct < 4; ++ct)
      vr[ct] = *(const uint4*)&vb[(size_t)(ct * 16 + l15) * Nsl +
                                  n0 + nh * 32 + lg * 8];

    f32x4 C1[4][2];
#pragma unroll
    for (int rt = 0; rt < 4; ++rt)
#pragma unroll
      for (int ct = 0; ct < 2; ++ct) C1[rt][ct] = (f32x4){0.f, 0.f, 0.f, 0.f};

#pragma unroll
    for (int ks = 0; ks < 8; ++ks) {
      const int c0 = ks * 32 + lg * 8;
      U16x4 a[4];
#pragma unroll
      for (int rt = 0; rt < 4; ++rt)
        a[rt].u = *(const uint4*)&Wqk2[(size_t)(h * 64 + rt * 16 + l15) * 256 + c0];
      bf8 Bf[2];
      {
        float f0[8], f1[8];
#pragma unroll
        for (int j = 0; j < 8; ++j) {
          const float* row = &xf[cur][(c0 + j) * 64];
          f0[j] = row[nr0];
          f1[j] = row[nr1];
        }
#pragma unroll
        for (int j = 0; j < 8; ++j) {
          Bf[0][j] = (short)f2bf(f0[j]);
          Bf[1][j] = (short)f2bf(f1[j]);
        }
      }
#pragma unroll
      for (int rt = 0; rt < 4; ++rt)
#pragma unroll
        for (int ct = 0; ct < 2; ++ct)
          C1[rt][ct] = __builtin_amdgcn_mfma_f32_16x16x32_bf16(
              a[rt].h, Bf[ct], C1[rt][ct], 0, 0, 0);
    }

#pragma unroll
    for (int ct = 0; ct < 2; ++ct) {
      float m = -1e30f;
#pragma unroll
      for (int rt = 0; rt < 2; ++rt)
#pragma unroll
        for (int r = 0; r < 4; ++r) m = fmaxf(m, C1[rt][ct][r]);
      m = fmaxf(m, __shfl_xor(m, 16));
      m = fmaxf(m, __shfl_xor(m, 32));
      float e[2][4], s = 0.f;
#pragma unroll
      for (int rt = 0; rt < 2; ++rt)
#pragma unroll
        for (int r = 0; r < 4; ++r) { e[rt][r] = __expf(C1[rt][ct][r] - m); s += e[rt][r]; }
      s += __shfl_xor(s, 16);
      s += __shfl_xor(s, 32);
      const float inv = 1.f / s;
      uint* qn = qhead + gn_base + n0 + ct * 16;     // + j*NPOS rows
#pragma unroll
      for (int rt = 0; rt < 2; ++rt) {
        const int j0 = rt * 8 + lg * 2;
        qn[(size_t)(j0 + 0) * NPOS] = pk2(e[rt][0] * inv, e[rt][1] * inv);
        qn[(size_t)(j0 + 1) * NPOS] = pk2(e[rt][2] * inv, e[rt][3] * inv);
      }
    }

#pragma unroll
    for (int rt2 = 0; rt2 < 2; ++rt2)
#pragma unroll
      for (int ct = 0; ct < 2; ++ct) {
        const int nl = ct * 16 + l15;
#pragma unroll
        for (int r = 0; r < 4; ++r)
          myscr[(rt2 * 16 + lg * 4 + r) * 40 + nl] =
              (short)f2bf(__expf(C1[rt2 + 2][ct][r]));
      }

    __asm__ __volatile__("" ::: "memory");
    bf8 A2[2];
#pragma unroll
    for (int rt2 = 0; rt2 < 2; ++rt2)
      A2[rt2] = *(const bf8*)&myscr[(rt2 * 16 + l15) * 40 + lg * 8];
#pragma unroll
    for (int rt2 = 0; rt2 < 2; ++rt2) {
#pragma unroll
      for (int ct = 0; ct < 4; ++ct) {
        U16x4 v_; v_.u = vr[ct];
        C2[rt2][ct] = __builtin_amdgcn_mfma_f32_16x16x32_bf16(
            A2[rt2], v_.h, C2[rt2][ct], 0, 0, 0);
      }
      C2[rt2][4] = __builtin_amdgcn_mfma_f32_16x16x32_bf16(
          A2[rt2], Bones, C2[rt2][4], 0, 0, 0);
    }

    cur ^= 1;
  }
#undef STAGE

  __syncthreads();
  float* comb = (float*)xf;
  if (nh == 1) {
    float* dst = comb + (h * 64 + lane) * 40;
#pragma unroll
    for (int rt2 = 0; rt2 < 2; ++rt2)
#pragma unroll
      for (int ct = 0; ct < 5; ++ct)
#pragma unroll
        for (int r = 0; r < 4; ++r)
          dst[rt2 * 20 + ct * 4 + r] = C2[rt2][ct][r];
  }
  __syncthreads();
  if (nh == 0) {
    const float* srcp = comb + (h * 64 + lane) * 40;
    float* pb = partials + (size_t)bid * PF2;
#pragma unroll
    for (int rt2 = 0; rt2 < 2; ++rt2)
#pragma unroll
      for (int ct = 0; ct < 5; ++ct)
#pragma unroll
        for (int r = 0; r < 4; ++r) {
          const float v2 = C2[rt2][ct][r] + srcp[rt2 * 20 + ct * 4 + r];
          const int row = h * 32 + rt2 * 16 + lg * 4 + r;
          const int col = ct * 16 + l15;
          const int idx = row * 80 + col;
          if (first) pb[idx] = v2;
          else       pb[idx] += v2;
        }
  }
}

// ---------------------------------------------------------------------------
// Reductions over pass-1 block partials (unchanged).
// ---------------------------------------------------------------------------
__global__ __launch_bounds__(256) void k_red_a(
    const float* __restrict__ partials, float* __restrict__ partial2, int nbh)
{
  const int bid = blockIdx.x;               // 2 * 8 * 40
  const int ec  = bid % 40, kc = (bid / 40) & 7, b = bid / 320;
  const int e   = ec * 256 + threadIdx.x;
  if (e >= PF2) return;
  const int kpc = nbh / 8;
  const float* pbase = partials + (size_t)(b * nbh + kc * kpc) * PF2 + e;
  float s0 = 0.f, s1 = 0.f, s2 = 0.f, s3 = 0.f;
  for (int k = 0; k < kpc; k += 4) {
    s0 += pbase[(size_t)(k + 0) * PF2];
    s1 += pbase[(size_t)(k + 1) * PF2];
    s2 += pbase[(size_t)(k + 2) * PF2];
    s3 += pbase[(size_t)(k + 3) * PF2];
  }
  partial2[(size_t)(b * 8 + kc) * PF2 + e] = (s0 + s1) + (s2 + s3);
}

__global__ __launch_bounds__(256) void k_red_s(
    const float* __restrict__ partial2, float* __restrict__ Sfin)
{
  const int t = threadIdx.x;                // 256 = 2b x 128 kc
  const int b = t >> 7, kc = t & 127;
  float s = 0.f;
#pragma unroll
  for (int j = 0; j < 8; ++j)
    s += partial2[(size_t)(b * 8 + j) * PF2 + kc * 80 + 64];
  Sfin[b * 128 + kc] = s;
}

__global__ __launch_bounds__(256) void k_red_b(
    const float* __restrict__ partial2, const float* __restrict__ Sfin,
    float* __restrict__ kvn)
{
  const int bid = blockIdx.x;               // 64 = 2b x 32
  const int chunk = bid & 31, b = bid >> 5;
  const int e = chunk * 256 + threadIdx.x;  // < 8192
  const int kc = e >> 6, dv = e & 63;
  float s = 0.f;
#pragma unroll
  for (int j = 0; j < 8; ++j)
    s += partial2[(size_t)(b * 8 + j) * PF2 + kc * 80 + dv];
  kvn[(size_t)b * 8192 + e] = s / (Sfin[b * 128 + kc] * (1.f + 1e-6f));
}

// ---------------------------------------------------------------------------
// k_out2: out[n][c] = qsm[n][.] · kvn. qsm reads coalesced (transposed).
// ---------------------------------------------------------------------------
__global__ __launch_bounds__(256) void k_out2(
    const uint* __restrict__ qsm, const float* __restrict__ kvn,
    float* __restrict__ out)
{
  const int t = threadIdx.x, lane = t & 63;
  const int w = __builtin_amdgcn_readfirstlane(t >> 6);
  const int bid = blockIdx.x;
  const int b  = bid / 1728;
  const int n0 = (bid % 1728) * 64;

  const uint* qp = qsm + (size_t)(b * 4 + w) * 16 * NPOS + n0 + lane;
  uint q[16];
#pragma unroll
  for (int j = 0; j < 16; ++j) q[j] = qp[(size_t)j * NPOS];
  float qa[32];
#pragma unroll
  for (int j = 0; j < 16; ++j) {
    qa[2 * j]     = __uint_as_float(q[j] << 16);
    qa[2 * j + 1] = __uint_as_float(q[j] & 0xFFFF0000u);
  }

  float oa[64];
#pragma unroll
  for (int d = 0; d < 64; ++d) oa[d] = 0.f;
  const float* kvh = kvn + (size_t)b * 8192 + (size_t)(w * 32) * 64;
#pragma unroll
  for (int kc = 0; kc < 32; ++kc) {
    const float* kr = kvh + kc * 64;
#pragma unroll
    for (int d = 0; d < 64; ++d) oa[d] = fmaf(qa[kc], kr[d], oa[d]);
  }
  float* ob = out + (size_t)(b * CH + w * DV) * NPOS + n0 + lane;
#pragma unroll
  for (int d = 0; d < 64; ++d) ob[(size_t)d * NPOS] = oa[d];
}

// ---------------------------------------------------------------------------
extern "C" void kernel_launch(void* const* d_in, const int* in_sizes, int n_in,
                              void* d_out, int out_size, void* d_ws, size_t ws_size,
                              hipStream_t stream)
{
  const float* x  = (const float*)d_in[0];
  const float* Wq = (const float*)d_in[1];
  const float* Wk = (const float*)d_in[2];
  const float* Wv = (const float*)d_in[3];
  const float* bv = (const float*)d_in[4];
  float* out = (float*)d_out;
  float* ws  = (float*)d_ws;

  // ws (u32 words): Wqk2 32768 | qsm 14155776 | kvn 16384 | Sfin 256 |
  //                 partial2 16*PF2 | partials 2*nbh*PF2 | vbuf bf16
  ushort* Wqk2    = (ushort*)ws;
  uint*   qsm     = (uint*)(ws + 32768);
  float*  kvn     = ws + 32768 + 14155776;
  float*  Sfin    = kvn + 16384;
  float*  partial2= Sfin + 256;
  const size_t fixed0 = 32768 + 14155776 + 16384 + 256 + (size_t)16 * PF2;
  float*  partials = partial2 + 16 * PF2;

  const size_t wsf = ws_size / 4;
  // ys must be a multiple of 12 (k_conv3 strips); nbh a multiple of 32 (k_red_a)
  static const int cand[][2] = {
    {128,48},{128,24},{64,24},{128,12},{64,12},{32,12}};
  int nbh = 32, ys = 12;
  for (int i = 0; i < 6; ++i) {
    const size_t need = fixed0 + (size_t)(2 * cand[i][0]) * PF2
                      + (size_t)cand[i][1] * 589824;
    if (need <= wsf) { nbh = cand[i][0]; ys = cand[i][1]; break; }
  }
  __hip_bfloat16* vbuf = (__hip_bfloat16*)(partials + (size_t)(2 * nbh) * PF2);

  k_prep2<<<256, 256, 0, stream>>>(Wq, Wk, Wqk2);

  const int nslab = 48 / ys;
  const int nyc = ys / 12;
  for (int s = 0; s < nslab; ++s) {
    k_conv3<<<2 * 256 * nyc, 192, 0, stream>>>(x, Wv, bv, vbuf, s * ys, ys, nyc);
    k_fuse <<<2 * nbh,       512, 0, stream>>>(x, Wqk2, (const ushort*)vbuf, qsm,
                                               partials, s * ys, ys,
                                               (s == 0) ? 1 : 0, nbh);
  }
  k_red_a<<<640, 256, 0, stream>>>(partials, partial2, nbh);
  k_red_s<<<1,   256, 0, stream>>>(partial2, Sfin);
  k_red_b<<<64,  256, 0, stream>>>(partial2, Sfin, kvn);
  k_out2 <<<2 * 1728, 256, 0, stream>>>(qsm, kvn, out);
}

// Round 19
// 293.135 us; speedup vs baseline: 1.0863x; 1.0863x over previous
//
#include <hip/hip_runtime.h>
#include <hip/hip_bf16.h>

static constexpr int CH   = 256;
static constexpr int NHD  = 4;
static constexpr int DV   = 64;
static constexpr int SY = 48, SX = 48, SZ = 48;
static constexpr int NPEN = SY * SX;     // 2304
static constexpr int NPOS = NPEN * SZ;   // 110592
static constexpr int PF2  = 128 * 80;    // kv partial floats per block

typedef float f32x4 __attribute__((ext_vector_type(4)));
typedef short bf8   __attribute__((ext_vector_type(8)));
union U16x4 { uint4 u; bf8 h; };

__device__ __forceinline__ ushort f2bf(float f) {
  return __bfloat16_as_ushort(__float2bfloat16(f));
}
__device__ __forceinline__ uint pk2(float lo, float hi) {
  return ((uint)f2bf(hi) << 16) | (uint)f2bf(lo);
}

// ---------------------------------------------------------------------------
// Prep: Wqk2 bf16 [256 rows][256 c], per-head blocks.
// ---------------------------------------------------------------------------
__global__ __launch_bounds__(256) void k_prep2(
    const float* __restrict__ Wq, const float* __restrict__ Wk,
    ushort* __restrict__ Wqk2)
{
  const int i = blockIdx.x * 256 + threadIdx.x;   // grid 256 -> 65536
  const int rp = i >> 8, c = i & 255;
  const int h = rp >> 6, s = (rp >> 5) & 1, j = rp & 31;
  const float v = s ? Wk[(h * 32 + j) * 256 + c] : Wq[(h * 32 + j) * 256 + c];
  Wqk2[i] = f2bf(v);
}

// ---------------------------------------------------------------------------
// k_conv3: depthwise 3x3x3 conv + bias -> v (bf16).
// Round-17 configuration (session-best, 131us): partial-sum carrying -- each
// plane read ONCE per thread (42 LDS reads/row) and folded immediately into
// three 12-float accumulators; 4-slot stride-51 ring, 1 barrier/row;
// VGPR ~80 (no cliff). Barrier-free (r18) and window-carry (r16) both lost.
// ---------------------------------------------------------------------------
__global__ __launch_bounds__(192) void k_conv3(
    const float* __restrict__ x, const float* __restrict__ Wv,
    const float* __restrict__ bv, __hip_bfloat16* __restrict__ vbuf,
    int y0s, int ys, int nyc)
{
  __shared__ float ring[4 * 2550];       // 4 planes [50][51], 40.8 KB

  const int t   = threadIdx.x;
  const int bid = blockIdx.x;
  const int yc  = bid % nyc;
  const int c   = (bid / nyc) & 255;
  const int b   = bid / (nyc * 256);
  const int yst = y0s + yc * 12;

  const int cu = __builtin_amdgcn_readfirstlane(c);
  const float* xc = x + (size_t)(b * CH + cu) * NPOS;
  float wreg[27];
#pragma unroll
  for (int j = 0; j < 27; ++j) wreg[j] = Wv[cu * 27 + j];
  const float bias = bv[cu];

  for (int i = t; i < 4 * 2550; i += 192) ring[i] = 0.f;

  // uniform staging: 3 float4 chunks per thread (576 total per row)
  const int k0 = t, k1 = t + 192, k2 = t + 384;
  const int o0 = (1 + k0 / 12) * 51 + 1 + (k0 % 12) * 4;
  const int o1 = (1 + k1 / 12) * 51 + 1 + (k1 % 12) * 4;
  const int o2 = (1 + k2 / 12) * 51 + 1 + (k2 % 12) * 4;

  float4 v0, v1, v2;

#define SISSUE(gy_)                                                           \
  {                                                                           \
    const int g_ = (gy_);                                                     \
    if ((unsigned)g_ < 48u) {                                                 \
      const float* rp_ = xc + (size_t)g_ * NPEN;                              \
      v0 = *(const float4*)(rp_ + k0 * 4);                                    \
      v1 = *(const float4*)(rp_ + k1 * 4);                                    \
      v2 = *(const float4*)(rp_ + k2 * 4);                                    \
    } else {                                                                  \
      v0 = (float4){0.f,0.f,0.f,0.f}; v1 = v0; v2 = v0;                       \
    }                                                                         \
  }

#define SWRITE(slot_)                                                         \
  {                                                                           \
    float* pl_ = ring + (slot_) * 2550;                                       \
    pl_[o0+0]=v0.x; pl_[o0+1]=v0.y; pl_[o0+2]=v0.z; pl_[o0+3]=v0.w;           \
    pl_[o1+0]=v1.x; pl_[o1+1]=v1.y; pl_[o1+2]=v1.z; pl_[o1+3]=v1.w;           \
    pl_[o2+0]=v2.x; pl_[o2+1]=v2.y; pl_[o2+2]=v2.z; pl_[o2+3]=v2.w;           \
  }

  __syncthreads();                       // memset done

  SISSUE(yst - 1) SWRITE(0)              // plane p=-1 (q=0)
  SISSUE(yst)     SWRITE(1)              // plane p=0  (q=1)
  SISSUE(yst + 1) SWRITE(2)              // plane p=1  (q=2)
  __syncthreads();

  const int xq = t >> 2;                 // 0..47 (all 3 waves compute)
  const int zb = (t & 3) * 12;

  float accA[12], accB[12], outv[12];
#pragma unroll
  for (int i = 0; i < 12; ++i) { accA[i] = bias; accB[i] = bias; }

  // FOLD3: plane at slot_ contributes ky=2 -> outv, ky=1 -> accA, ky=0 -> accB
#define FOLD3(slot_)                                                          \
  {                                                                           \
    const float* P_ = ring + (slot_) * 2550;                                  \
    _Pragma("unroll")                                                         \
    for (int dx = 0; dx < 3; ++dx) {                                          \
      const float* B_ = P_ + (xq + dx) * 51 + zb;                             \
      float col[14];                                                          \
      _Pragma("unroll")                                                       \
      for (int k = 0; k < 14; ++k) col[k] = B_[k];                            \
      _Pragma("unroll")                                                       \
      for (int dz = 0; dz < 3; ++dz) {                                        \
        const float w2_ = wreg[18 + dx * 3 + dz];                             \
        const float w1_ = wreg[9  + dx * 3 + dz];                             \
        const float w0_ = wreg[     dx * 3 + dz];                             \
        _Pragma("unroll")                                                     \
        for (int i = 0; i < 12; ++i) {                                        \
          outv[i] = fmaf(w2_, col[i + dz], outv[i]);                          \
          accA[i] = fmaf(w1_, col[i + dz], accA[i]);                          \
          accB[i] = fmaf(w0_, col[i + dz], accB[i]);                          \
        }                                                                     \
      }                                                                       \
    }                                                                         \
  }

  // prologue folds: plane p=-1 (slot 0, ky=0 for out 0) -> accA;
  //                 plane p=0  (slot 1, ky=1 -> accA, ky=0 -> accB)
  {
    const float* P_ = ring + 0 * 2550;
#pragma unroll
    for (int dx = 0; dx < 3; ++dx) {
      const float* B_ = P_ + (xq + dx) * 51 + zb;
      float col[14];
#pragma unroll
      for (int k = 0; k < 14; ++k) col[k] = B_[k];
#pragma unroll
      for (int dz = 0; dz < 3; ++dz) {
        const float w0_ = wreg[dx * 3 + dz];
#pragma unroll
        for (int i = 0; i < 12; ++i)
          accA[i] = fmaf(w0_, col[i + dz], accA[i]);
      }
    }
  }
  {
    const float* P_ = ring + 1 * 2550;
#pragma unroll
    for (int dx = 0; dx < 3; ++dx) {
      const float* B_ = P_ + (xq + dx) * 51 + zb;
      float col[14];
#pragma unroll
      for (int k = 0; k < 14; ++k) col[k] = B_[k];
#pragma unroll
      for (int dz = 0; dz < 3; ++dz) {
        const float w1_ = wreg[9 + dx * 3 + dz];
        const float w0_ = wreg[    dx * 3 + dz];
#pragma unroll
        for (int i = 0; i < 12; ++i) {
          accA[i] = fmaf(w1_, col[i + dz], accA[i]);
          accB[i] = fmaf(w0_, col[i + dz], accB[i]);
        }
      }
    }
  }

  for (int r = 0; r < 12; ++r) {
    if (r < 11) SISSUE(yst + r + 2)      // stage plane p=r+2 (issue early)

    // rotate accumulators: outv <- accA (partial for out r), accA <- accB,
    // accB <- bias (out r+2 starts fresh)
#pragma unroll
    for (int i = 0; i < 12; ++i) {
      outv[i] = accA[i];
      accA[i] = accB[i];
      accB[i] = bias;
    }
    FOLD3((r + 2) & 3)                   // plane p=r+1: ky2/ky1/ky0 folds

    {
      const size_t o = (size_t)(b * CH + cu) * ((size_t)ys * NPEN) +
                       (size_t)(yst - y0s + r) * NPEN + xq * SZ + zb;
      uint2 s0, s1, s2;
      s0.x = pk2(outv[0], outv[1]);  s0.y = pk2(outv[2],  outv[3]);
      s1.x = pk2(outv[4], outv[5]);  s1.y = pk2(outv[6],  outv[7]);
      s2.x = pk2(outv[8], outv[9]);  s2.y = pk2(outv[10], outv[11]);
      __hip_bfloat16* dst = vbuf + o;
      *(uint2*)(dst)     = s0;
      *(uint2*)(dst + 4) = s1;
      *(uint2*)(dst + 8) = s2;
    }

    if (r < 11) SWRITE((r + 3) & 3)      // plane p=r+2 into oldest slot
    __syncthreads();
  }
#undef FOLD3
#undef SISSUE
#undef SWRITE
}

// ---------------------------------------------------------------------------
// k_fuse: 512 thr, 8 waves. wave w -> head h=w>>1, n-half nh=w&1.
// Double-buffered gload_lds x-tile; rotated bank-free layout; transposed qsm.
// ---------------------------------------------------------------------------
__global__ __launch_bounds__(512) void k_fuse(
    const float* __restrict__ x, const ushort* __restrict__ Wqk2,
    const ushort* __restrict__ vbuf, uint* __restrict__ qsm,
    float* __restrict__ partials, int y0s, int ys, int first, int nbh)
{
  __shared__ float xf[2][CH * 64];      // 2 x 64 KB f32 x-tile [c][64n] rotated
  __shared__ short scr[8 * 32 * 40];    // per-wave wexp [kc][40] (80B rows)

  const int t    = threadIdx.x;
  const int lane = t & 63;
  const int w    = __builtin_amdgcn_readfirstlane(t >> 6);
  const int h    = w >> 1, nh = w & 1;
  const int l15  = lane & 15, lg = lane >> 4;
  const int bid  = blockIdx.x;
  const int b    = (bid >= nbh) ? 1 : 0;
  const int bh   = bid - b * nbh;
  const int ntiles = ys * 36;
  const size_t Nsl = (size_t)ys * NPEN;

  const float*  xb = x + (size_t)b * CH * NPOS + (size_t)y0s * NPEN;
  const ushort* vb = vbuf + (size_t)(b * CH + h * 64) * Nsl;
  short* myscr = &scr[w * 32 * 40];
  const int gn_base = y0s * NPEN + nh * 32 + l15;
  uint* qhead = qsm + (size_t)(b * 4 + h) * 16 * NPOS;

  bf8 Bones;
  {
    const short o = (l15 == 0) ? (short)0x3F80 : (short)0;
#pragma unroll
    for (int j = 0; j < 8; ++j) Bones[j] = o;
  }

  f32x4 C2[2][5];
#pragma unroll
  for (int i = 0; i < 2; ++i)
#pragma unroll
    for (int j = 0; j < 5; ++j) C2[i][j] = (f32x4){0.f, 0.f, 0.f, 0.f};

  const int nr0 = (nh * 32 + 0  + l15 + lg * 8) & 63;
  const int nr1 = (nh * 32 + 16 + l15 + lg * 8) & 63;

#define STAGE(tile_, buf_)                                                     \
  {                                                                            \
    const int n0_ = (tile_) * 64;                                              \
    _Pragma("unroll")                                                          \
    for (int j_ = 0; j_ < 8; ++j_) {                                           \
      const int k_  = j_ * 512 + t;           /* 16B chunk id, 0..4095 */      \
      const int c_  = k_ >> 4;                                                 \
      const int ci_ = k_ & 15;                                                 \
      const int rot_ = ((c_ >> 3) & 3) << 1;  /* rotation in 16B chunks */     \
      const int nq_  = ((ci_ - rot_) & 15) << 2;                               \
      const float* src_ = xb + (size_t)c_ * NPOS + n0_ + nq_;                  \
      __builtin_amdgcn_global_load_lds(                                        \
          (const __attribute__((address_space(1))) void*)src_,                 \
          (__attribute__((address_space(3))) void*)((char*)xf +                \
              ((buf_) * 4096 + j_ * 512 + w * 64) * 16),                       \
          16, 0, 0);                                                           \
    }                                                                          \
  }

  int cur = 0;
  if (bh < ntiles) STAGE(bh, 0)

  for (int tile = bh; tile < ntiles; tile += nbh) {
    const int n0 = tile * 64;
    __syncthreads();                       // xf[cur] ready (drain); waves sync

    if (tile + nbh < ntiles) STAGE(tile + nbh, cur ^ 1)

    uint4 vr[4];
#pragma unroll
    for (int ct = 0; ct < 4; ++ct)
      vr[ct] = *(const uint4*)&vb[(size_t)(ct * 16 + l15) * Nsl +
                                  n0 + nh * 32 + lg * 8];

    f32x4 C1[4][2];
#pragma unroll
    for (int rt = 0; rt < 4; ++rt)
#pragma unroll
      for (int ct = 0; ct < 2; ++ct) C1[rt][ct] = (f32x4){0.f, 0.f, 0.f, 0.f};

#pragma unroll
    for (int ks = 0; ks < 8; ++ks) {
      const int c0 = ks * 32 + lg * 8;
      U16x4 a[4];
#pragma unroll
      for (int rt = 0; rt < 4; ++rt)
        a[rt].u = *(const uint4*)&Wqk2[(size_t)(h * 64 + rt * 16 + l15) * 256 + c0];
      bf8 Bf[2];
      {
        float f0[8], f1[8];
#pragma unroll
        for (int j = 0; j < 8; ++j) {
          const float* row = &xf[cur][(c0 + j) * 64];
          f0[j] = row[nr0];
          f1[j] = row[nr1];
        }
#pragma unroll
        for (int j = 0; j < 8; ++j) {
          Bf[0][j] = (short)f2bf(f0[j]);
          Bf[1][j] = (short)f2bf(f1[j]);
        }
      }
#pragma unroll
      for (int rt = 0; rt < 4; ++rt)
#pragma unroll
        for (int ct = 0; ct < 2; ++ct)
          C1[rt][ct] = __builtin_amdgcn_mfma_f32_16x16x32_bf16(
              a[rt].h, Bf[ct], C1[rt][ct], 0, 0, 0);
    }

#pragma unroll
    for (int ct = 0; ct < 2; ++ct) {
      float m = -1e30f;
#pragma unroll
      for (int rt = 0; rt < 2; ++rt)
#pragma unroll
        for (int r = 0; r < 4; ++r) m = fmaxf(m, C1[rt][ct][r]);
      m = fmaxf(m, __shfl_xor(m, 16));
      m = fmaxf(m, __shfl_xor(m, 32));
      float e[2][4], s = 0.f;
#pragma unroll
      for (int rt = 0; rt < 2; ++rt)
#pragma unroll
        for (int r = 0; r < 4; ++r) { e[rt][r] = __expf(C1[rt][ct][r] - m); s += e[rt][r]; }
      s += __shfl_xor(s, 16);
      s += __shfl_xor(s, 32);
      const float inv = 1.f / s;
      uint* qn = qhead + gn_base + n0 + ct * 16;     // + j*NPOS rows
#pragma unroll
      for (int rt = 0; rt < 2; ++rt) {
        const int j0 = rt * 8 + lg * 2;
        qn[(size_t)(j0 + 0) * NPOS] = pk2(e[rt][0] * inv, e[rt][1] * inv);
        qn[(size_t)(j0 + 1) * NPOS] = pk2(e[rt][2] * inv, e[rt][3] * inv);
      }
    }

#pragma unroll
    for (int rt2 = 0; rt2 < 2; ++rt2)
#pragma unroll
      for (int ct = 0; ct < 2; ++ct) {
        const int nl = ct * 16 + l15;
#pragma unroll
        for (int r = 0; r < 4; ++r)
          myscr[(rt2 * 16 + lg * 4 + r) * 40 + nl] =
              (short)f2bf(__expf(C1[rt2 + 2][ct][r]));
      }

    __asm__ __volatile__("" ::: "memory");
    bf8 A2[2];
#pragma unroll
    for (int rt2 = 0; rt2 < 2; ++rt2)
      A2[rt2] = *(const bf8*)&myscr[(rt2 * 16 + l15) * 40 + lg * 8];
#pragma unroll
    for (int rt2 = 0; rt2 < 2; ++rt2) {
#pragma unroll
      for (int ct = 0; ct < 4; ++ct) {
        U16x4 v_; v_.u = vr[ct];
        C2[rt2][ct] = __builtin_amdgcn_mfma_f32_16x16x32_bf16(
            A2[rt2], v_.h, C2[rt2][ct], 0, 0, 0);
      }
      C2[rt2][4] = __builtin_amdgcn_mfma_f32_16x16x32_bf16(
          A2[rt2], Bones, C2[rt2][4], 0, 0, 0);
    }

    cur ^= 1;
  }
#undef STAGE

  __syncthreads();
  float* comb = (float*)xf;
  if (nh == 1) {
    float* dst = comb + (h * 64 + lane) * 40;
#pragma unroll
    for (int rt2 = 0; rt2 < 2; ++rt2)
#pragma unroll
      for (int ct = 0; ct < 5; ++ct)
#pragma unroll
        for (int r = 0; r < 4; ++r)
          dst[rt2 * 20 + ct * 4 + r] = C2[rt2][ct][r];
  }
  __syncthreads();
  if (nh == 0) {
    const float* srcp = comb + (h * 64 + lane) * 40;
    float* pb = partials + (size_t)bid * PF2;
#pragma unroll
    for (int rt2 = 0; rt2 < 2; ++rt2)
#pragma unroll
      for (int ct = 0; ct < 5; ++ct)
#pragma unroll
        for (int r = 0; r < 4; ++r) {
          const float v2 = C2[rt2][ct][r] + srcp[rt2 * 20 + ct * 4 + r];
          const int row = h * 32 + rt2 * 16 + lg * 4 + r;
          const int col = ct * 16 + l15;
          const int idx = row * 80 + col;
          if (first) pb[idx] = v2;
          else       pb[idx] += v2;
        }
  }
}

// ---------------------------------------------------------------------------
// Reductions over pass-1 block partials (unchanged).
// ---------------------------------------------------------------------------
__global__ __launch_bounds__(256) void k_red_a(
    const float* __restrict__ partials, float* __restrict__ partial2, int nbh)
{
  const int bid = blockIdx.x;               // 2 * 8 * 40
  const int ec  = bid % 40, kc = (bid / 40) & 7, b = bid / 320;
  const int e   = ec * 256 + threadIdx.x;
  if (e >= PF2) return;
  const int kpc = nbh / 8;
  const float* pbase = partials + (size_t)(b * nbh + kc * kpc) * PF2 + e;
  float s0 = 0.f, s1 = 0.f, s2 = 0.f, s3 = 0.f;
  for (int k = 0; k < kpc; k += 4) {
    s0 += pbase[(size_t)(k + 0) * PF2];
    s1 += pbase[(size_t)(k + 1) * PF2];
    s2 += pbase[(size_t)(k + 2) * PF2];
    s3 += pbase[(size_t)(k + 3) * PF2];
  }
  partial2[(size_t)(b * 8 + kc) * PF2 + e] = (s0 + s1) + (s2 + s3);
}

__global__ __launch_bounds__(256) void k_red_s(
    const float* __restrict__ partial2, float* __restrict__ Sfin)
{
  const int t = threadIdx.x;                // 256 = 2b x 128 kc
  const int b = t >> 7, kc = t & 127;
  float s = 0.f;
#pragma unroll
  for (int j = 0; j < 8; ++j)
    s += partial2[(size_t)(b * 8 + j) * PF2 + kc * 80 + 64];
  Sfin[b * 128 + kc] = s;
}

__global__ __launch_bounds__(256) void k_red_b(
    const float* __restrict__ partial2, const float* __restrict__ Sfin,
    float* __restrict__ kvn)
{
  const int bid = blockIdx.x;               // 64 = 2b x 32
  const int chunk = bid & 31, b = bid >> 5;
  const int e = chunk * 256 + threadIdx.x;  // < 8192
  const int kc = e >> 6, dv = e & 63;
  float s = 0.f;
#pragma unroll
  for (int j = 0; j < 8; ++j)
    s += partial2[(size_t)(b * 8 + j) * PF2 + kc * 80 + dv];
  kvn[(size_t)b * 8192 + e] = s / (Sfin[b * 128 + kc] * (1.f + 1e-6f));
}

// ---------------------------------------------------------------------------
// k_out2: out[n][c] = qsm[n][.] · kvn. qsm reads coalesced (transposed).
// ---------------------------------------------------------------------------
__global__ __launch_bounds__(256) void k_out2(
    const uint* __restrict__ qsm, const float* __restrict__ kvn,
    float* __restrict__ out)
{
  const int t = threadIdx.x, lane = t & 63;
  const int w = __builtin_amdgcn_readfirstlane(t >> 6);
  const int bid = blockIdx.x;
  const int b  = bid / 1728;
  const int n0 = (bid % 1728) * 64;

  const uint* qp = qsm + (size_t)(b * 4 + w) * 16 * NPOS + n0 + lane;
  uint q[16];
#pragma unroll
  for (int j = 0; j < 16; ++j) q[j] = qp[(size_t)j * NPOS];
  float qa[32];
#pragma unroll
  for (int j = 0; j < 16; ++j) {
    qa[2 * j]     = __uint_as_float(q[j] << 16);
    qa[2 * j + 1] = __uint_as_float(q[j] & 0xFFFF0000u);
  }

  float oa[64];
#pragma unroll
  for (int d = 0; d < 64; ++d) oa[d] = 0.f;
  const float* kvh = kvn + (size_t)b * 8192 + (size_t)(w * 32) * 64;
#pragma unroll
  for (int kc = 0; kc < 32; ++kc) {
    const float* kr = kvh + kc * 64;
#pragma unroll
    for (int d = 0; d < 64; ++d) oa[d] = fmaf(qa[kc], kr[d], oa[d]);
  }
  float* ob = out + (size_t)(b * CH + w * DV) * NPOS + n0 + lane;
#pragma unroll
  for (int d = 0; d < 64; ++d) ob[(size_t)d * NPOS] = oa[d];
}

// ---------------------------------------------------------------------------
extern "C" void kernel_launch(void* const* d_in, const int* in_sizes, int n_in,
                              void* d_out, int out_size, void* d_ws, size_t ws_size,
                              hipStream_t stream)
{
  const float* x  = (const float*)d_in[0];
  const float* Wq = (const float*)d_in[1];
  const float* Wk = (const float*)d_in[2];
  const float* Wv = (const float*)d_in[3];
  const float* bv = (const float*)d_in[4];
  float* out = (float*)d_out;
  float* ws  = (float*)d_ws;

  // ws (u32 words): Wqk2 32768 | qsm 14155776 | kvn 16384 | Sfin 256 |
  //                 partial2 16*PF2 | partials 2*nbh*PF2 | vbuf bf16
  ushort* Wqk2    = (ushort*)ws;
  uint*   qsm     = (uint*)(ws + 32768);
  float*  kvn     = ws + 32768 + 14155776;
  float*  Sfin    = kvn + 16384;
  float*  partial2= Sfin + 256;
  const size_t fixed0 = 32768 + 14155776 + 16384 + 256 + (size_t)16 * PF2;
  float*  partials = partial2 + 16 * PF2;

  const size_t wsf = ws_size / 4;
  // ys must be a multiple of 12 (k_conv3 strips); nbh a multiple of 32 (k_red_a)
  static const int cand[][2] = {
    {128,48},{128,24},{64,24},{128,12},{64,12},{32,12}};
  int nbh = 32, ys = 12;
  for (int i = 0; i < 6; ++i) {
    const size_t need = fixed0 + (size_t)(2 * cand[i][0]) * PF2
                      + (size_t)cand[i][1] * 589824;
    if (need <= wsf) { nbh = cand[i][0]; ys = cand[i][1]; break; }
  }
  __hip_bfloat16* vbuf = (__hip_bfloat16*)(partials + (size_t)(2 * nbh) * PF2);

  k_prep2<<<256, 256, 0, stream>>>(Wq, Wk, Wqk2);

  const int nslab = 48 / ys;
  const int nyc = ys / 12;
  for (int s = 0; s < nslab; ++s) {
    k_conv3<<<2 * 256 * nyc, 192, 0, stream>>>(x, Wv, bv, vbuf, s * ys, ys, nyc);
    k_fuse <<<2 * nbh,       512, 0, stream>>>(x, Wqk2, (const ushort*)vbuf, qsm,
                                               partials, s * ys, ys,
                                               (s == 0) ? 1 : 0, nbh);
  }
  k_red_a<<<640, 256, 0, stream>>>(partials, partial2, nbh);
  k_red_s<<<1,   256, 0, stream>>>(partial2, Sfin);
  k_red_b<<<64,  256, 0, stream>>>(partial2, Sfin, kvn);
  k_out2 <<<2 * 1728, 256, 0, stream>>>(qsm, kvn, out);
}